// Round 21
// baseline (153.916 us; speedup 1.0000x reference)
//
#include <hip/hip_runtime.h>
#include <math.h>

#define NB 8
#define NS 512
#define NE 32
#define DE 256
#define DH 512
#define DA 200
#define DAP 224   // padded att dim (7 tiles of 32)
#define NJ 7

typedef __bf16 bf16x8 __attribute__((ext_vector_type(8)));
typedef float f32x16 __attribute__((ext_vector_type(16)));

__device__ __forceinline__ float tanh_fast(float x) {
    float e = __expf(x + x);
    return fmaf(-2.f, __builtin_amdgcn_rcpf(e + 1.f), 1.f);
}

// ---- stage 1: partial sums of cxt over s-chunks (512 blocks) ----
__global__ __launch_bounds__(256) void cmean_partial(const float* __restrict__ cxt,
                                                     float* __restrict__ psum) {
    const int g = blockIdx.x;       // b*64 + c
    const int b = g >> 6, c = g & 63;
    const int t = threadIdx.x;
    const float* base = cxt + ((size_t)b * NS + c * 8) * DH;
    float s0 = 0.f, s1 = 0.f;
    #pragma unroll
    for (int s = 0; s < 8; ++s) {
        s0 += base[s * DH + t];
        s1 += base[s * DH + t + 256];
    }
    psum[(size_t)g * DH + t]       = s0;
    psum[(size_t)g * DH + t + 256] = s1;
}

// ---- stage 2: reduce partials -> cmean; hatt[b][a] = cmean @ Wh (zero-padded) ----
__global__ __launch_bounds__(256) void hatt_from_psum(const float* __restrict__ psum,
                                                      const float* __restrict__ Wh,
                                                      float* __restrict__ hattw) {
    const int b = blockIdx.x;
    const int t = threadIdx.x;
    __shared__ float cm[DH];
    float s0 = 0.f, s1 = 0.f;
    for (int c = 0; c < 64; ++c) {
        s0 += psum[((size_t)b * 64 + c) * DH + t];
        s1 += psum[((size_t)b * 64 + c) * DH + t + 256];
    }
    cm[t]       = s0 * (1.f / NS);
    cm[t + 256] = s1 * (1.f / NS);
    __syncthreads();
    if (t < DAP) {
        float acc = 0.f;
        if (t < DA)
            for (int h = 0; h < DH; ++h)
                acc = fmaf(cm[h], Wh[h * DA + t], acc);
        hattw[b * DAP + t] = acc;
    }
}

// ---- stage 3: pack We into bf16 B-fragment layout (zero-padded cols) ----
__global__ __launch_bounds__(64) void wef_build(const float* __restrict__ We,
                                                __bf16* __restrict__ wef) {
    const int f = blockIdx.x;
    const int l = threadIdx.x;
    const int nj = f >> 4, kk = f & 15;
    const int n = nj * 32 + (l & 31);
    bf16x8 v;
    #pragma unroll
    for (int e = 0; e < 8; ++e) {
        int K = kk * 16 + ((l >> 5) << 2) + (e & 3) + 8 * (e >> 2);
        v[e] = (__bf16)((n < DA) ? We[K * DA + n] : 0.f);
    }
    reinterpret_cast<bf16x8*>(wef)[f * 64 + l] = v;
}

// ---- stage 4: streaming pre-transpose of ent into bf16 A-fragment order ----
// (r18-verified correct.) Contiguous 32KB read -> padded LDS -> contiguous
// 16KB fragment write. A[kk] lane(m,hi) = row m cols {kk*16+hi*4+0..3,+8..11}.
__global__ __launch_bounds__(256) void entf_build(const float* __restrict__ ent,
                                                  __bf16* __restrict__ entf) {
    const int bs = blockIdx.x;
    const int t  = threadIdx.x;
    __shared__ float L[32 * 260];   // +4 pad per row
    const float4* s4 = reinterpret_cast<const float4*>(ent + (size_t)bs * 8192);
    #pragma unroll
    for (int i = 0; i < 8; ++i) {
        float4 v = s4[t + i * 256];            // contiguous across block
        int f4 = t + i * 256;
        int m = f4 >> 6, c4 = f4 & 63;
        *reinterpret_cast<float4*>(&L[m * 260 + c4 * 4]) = v;
    }
    __syncthreads();
    bf16x8* dst = reinterpret_cast<bf16x8*>(entf) + (size_t)bs * 1024;
    #pragma unroll
    for (int q = 0; q < 4; ++q) {
        int idx  = q * 256 + t;                // kk*64 + lane
        int kk   = idx >> 6, lane = idx & 63;
        int m    = lane & 31, hi = lane >> 5;
        const float* p = &L[m * 260 + kk * 16 + hi * 4];
        bf16x8 v = { (__bf16)p[0], (__bf16)p[1], (__bf16)p[2],  (__bf16)p[3],
                     (__bf16)p[8], (__bf16)p[9], (__bf16)p[10], (__bf16)p[11] };
        dst[idx] = v;                          // contiguous across block
    }
}

// ---- main: bf16-only, barrier-free, one tile per wave, reg-epilogue ----
// NEVER touches fp32 ent (r18's hidden cost: its epilogue re-read 128MB
// through the ~1.8TB/s scattered path). A-frags: 16 contiguous 1KB bf16
// loads. B streamed from L2-hot wef. Epilogue: per-lane row weight x A-frag
// registers, 5-step shfl_xor butterfly per kk -> column sums in-register.
__global__ __launch_bounds__(256) void entatt_main_frag(const __bf16* __restrict__ entf,
                                                        const __bf16* __restrict__ wef,
                                                        const float* __restrict__ hattw,
                                                        const float* __restrict__ Ws,
                                                        float* __restrict__ out) {
    const int t    = threadIdx.x;
    const int lane = t & 63;
    const int wid  = t >> 6;            // 0..3
    const int bs   = blockIdx.x * 4 + wid;
    const int b    = bs >> 9;           // NS = 512
    const int m    = lane & 31;
    const int hi   = lane >> 5;

    __shared__ float lg_lds[4][NE];

    // ---- A fragments: 16 lane-linear contiguous 1KB bf16 loads ----
    const bf16x8* ef8 = reinterpret_cast<const bf16x8*>(entf) + (size_t)bs * 1024 + lane;
    bf16x8 A[16];
    #pragma unroll
    for (int kk = 0; kk < 16; ++kk) A[kk] = ef8[kk * 64];

    // per-lane att-column scalars for all 7 nj tiles
    const float* hb = hattw + b * DAP;
    float ha_[NJ], wsa_[NJ];
    #pragma unroll
    for (int nj = 0; nj < NJ; ++nj) {
        const int a = nj * 32 + m;
        ha_[nj]  = hb[a];
        wsa_[nj] = (a < DA) ? Ws[a] : 0.f;
    }

    const bf16x8* wg8 = reinterpret_cast<const bf16x8*>(wef);

    // ---- MFMA over 7 nj tiles; B streamed from L2-resident wef ----
    float part[16];
    #pragma unroll
    for (int r = 0; r < 16; ++r) part[r] = 0.f;

    #pragma unroll 1
    for (int nj = 0; nj < NJ; ++nj) {
        f32x16 acc;
        #pragma unroll
        for (int r = 0; r < 16; ++r) acc[r] = 0.f;
        #pragma unroll
        for (int kk = 0; kk < 16; ++kk)
            acc = __builtin_amdgcn_mfma_f32_32x32x16_bf16(
                      A[kk], wg8[(nj * 16 + kk) * 64 + lane], acc, 0, 0, 0);
        const float ha = ha_[nj], wsa = wsa_[nj];
        #pragma unroll
        for (int r = 0; r < 16; ++r)
            part[r] = fmaf(tanh_fast(acc[r] + ha), wsa, part[r]);
    }

    // ---- logits: reduce over 32 a-cols; per-wave LDS scratch (r5-verified) ----
    #pragma unroll
    for (int r = 0; r < 16; ++r) {
        float v = part[r];
        v += __shfl_xor(v, 1);  v += __shfl_xor(v, 2);  v += __shfl_xor(v, 4);
        v += __shfl_xor(v, 8);  v += __shfl_xor(v, 16);
        part[r] = v;
    }
    if (m == 0) {
        #pragma unroll
        for (int r = 0; r < 16; ++r)
            lg_lds[wid][(r & 3) + 8 * (r >> 2) + 4 * hi] = part[r];
    }
    // same-wave LDS RAW: compiler inserts lgkmcnt wait; no barrier needed

    // ---- softmax over entities ----
    float mx = -1e30f;
    #pragma unroll
    for (int e = 0; e < NE; ++e) mx = fmaxf(mx, lg_lds[wid][e]);
    float wsum = 0.f;
    #pragma unroll
    for (int e = 0; e < NE; ++e) wsum += __expf(lg_lds[wid][e] - mx);
    const float inv = __builtin_amdgcn_rcpf(wsum);
    const float wm  = __expf(lg_lds[wid][m] - mx) * inv;   // this lane's row weight

    // ---- epilogue from registers: out[c] = sum_m wm[m] * ent[m][c] ----
    // Lane (m,hi) holds row m cols {kk*16+hi*4+0..3, +8..11}; butterfly over
    // the 32-lane group sums rows. Lane m==kk writes its kk's 8 columns.
    float* outb = out + (size_t)bs * 256;
    #pragma unroll
    for (int kk = 0; kk < 16; ++kk) {
        float s0 = (float)A[kk][0] * wm, s1 = (float)A[kk][1] * wm;
        float s2 = (float)A[kk][2] * wm, s3 = (float)A[kk][3] * wm;
        float s4 = (float)A[kk][4] * wm, s5 = (float)A[kk][5] * wm;
        float s6 = (float)A[kk][6] * wm, s7 = (float)A[kk][7] * wm;
        #pragma unroll
        for (int d = 1; d <= 16; d <<= 1) {
            s0 += __shfl_xor(s0, d);  s1 += __shfl_xor(s1, d);
            s2 += __shfl_xor(s2, d);  s3 += __shfl_xor(s3, d);
            s4 += __shfl_xor(s4, d);  s5 += __shfl_xor(s5, d);
            s6 += __shfl_xor(s6, d);  s7 += __shfl_xor(s7, d);
        }
        if (m == kk) {
            *reinterpret_cast<float4*>(outb + kk * 16 + hi * 4)     = make_float4(s0, s1, s2, s3);
            *reinterpret_cast<float4*>(outb + kk * 16 + hi * 4 + 8) = make_float4(s4, s5, s6, s7);
        }
    }
}

extern "C" void kernel_launch(void* const* d_in, const int* in_sizes, int n_in,
                              void* d_out, int out_size, void* d_ws, size_t ws_size,
                              hipStream_t stream) {
    const float* cxt = (const float*)d_in[0];
    const float* ent = (const float*)d_in[1];
    const float* We  = (const float*)d_in[2];
    const float* Wh  = (const float*)d_in[3];
    const float* Ws  = (const float*)d_in[4];
    float* out = (float*)d_out;

    char* ws = (char*)d_ws;
    float*  psum  = (float*)ws;                          // 1 MB
    float*  hattw = (float*)(ws + 512 * DH * 4);         // 7 KB
    __bf16* wef   = (__bf16*)(ws + 512 * DH * 4 + NB * DAP * 4);   // 112 KB
    const size_t entf_off = 512 * DH * 4 + NB * DAP * 4 + (size_t)NJ * 16 * 512 * 2;
    __bf16* entf  = (__bf16*)(ws + entf_off);            // 64 MB
    (void)ws_size;

    hipLaunchKernelGGL(entf_build, dim3(NB * NS), dim3(256), 0, stream, ent, entf);
    hipLaunchKernelGGL(wef_build, dim3(NJ * 16), dim3(64), 0, stream, We, wef);
    hipLaunchKernelGGL(cmean_partial, dim3(512), dim3(256), 0, stream, cxt, psum);
    hipLaunchKernelGGL(hatt_from_psum, dim3(NB), dim3(256), 0, stream, psum, Wh, hattw);
    hipLaunchKernelGGL(entatt_main_frag, dim3(1024), dim3(256), 0, stream,
                       entf, wef, hattw, Ws, out);
}